// Round 9
// baseline (240.365 us; speedup 1.0000x reference)
//
#include <hip/hip_runtime.h>
#include <math.h>

// ---------------------------------------------------------------------------
// CausalSelfAttention fused pipeline, MI355X gfx950.  Round 9.
// r8: 237us. QKV gemm stuck at 99us / MfmaUtil 9.7% — global_load_lds dbuf
// neutral (m99/m100 replication): compiler's vmcnt(0)-before-s_barrier drains
// the prefetch after only one short compute phase. This round: REGISTER-
// PREFETCH pipeline — buffer_load->VGPR issued after the publishing barrier,
// ds_write_b128 at next iter top; the vmcnt wait moves off the barrier onto
// the ds_write, one full compute phase + 2 barriers later. BK=32, 16KB LDS.
// attn3 / gate / convert unchanged (r6/r7-verified).
// Workspace: q(=y) 8MB | k 8MB | vt 8MB | xb 8MB | w[4]b 8MB | gate 256KB.
// ---------------------------------------------------------------------------

#define B_    2
#define T_    2048
#define DIM_  1024
#define H_    16
#define HD_   64
#define NROW  (B_ * T_)
#define EPS_  1.1920929e-07f
#define SCALE_ 0.1f
#define LOG2_10K 13.287712379549449f

typedef unsigned short u16;
typedef unsigned int   u32;
typedef __bf16 bf16x8 __attribute__((ext_vector_type(8)));
typedef __bf16 bf16x2 __attribute__((ext_vector_type(2)));
typedef float  f32x4  __attribute__((ext_vector_type(4)));

__device__ __forceinline__ u16 f2b(float f) {
  u32 u = __float_as_uint(f);
  u += 0x7fffu + ((u >> 16) & 1u);       // RNE
  return (u16)(u >> 16);
}
__device__ __forceinline__ u32 pk2(float a, float b) {
#if __has_builtin(__builtin_amdgcn_cvt_pk_bf16_f32)
  bf16x2 r = __builtin_amdgcn_cvt_pk_bf16_f32(a, b);
  return __builtin_bit_cast(u32, r);
#else
  return (u32)f2b(a) | ((u32)f2b(b) << 16);
#endif
}
#define MFMA16(a,b,c) __builtin_amdgcn_mfma_f32_16x16x32_bf16((a),(b),(c),0,0,0)

// ---------------------------------------------------------------------------
// Convert pass: x (4M) and Wq/Wk/Wv/Wp (1M each) f32 -> bf16.
// ---------------------------------------------------------------------------
__global__ __launch_bounds__(256) void convert_all(
    const float* __restrict__ x, const float* __restrict__ Wq,
    const float* __restrict__ Wk, const float* __restrict__ Wv,
    const float* __restrict__ Wp,
    u16* __restrict__ xb, u16* __restrict__ wb /* wqb|wkb|wvb|wpb */) {
  const int i = blockIdx.x * 256 + threadIdx.x;       // 0 .. 2M-1 groups
  const float* src;
  u16* dst;
  int off;
  if (i < 1048576)       { src = x;  dst = xb;            off = i; }
  else if (i < 1310720)  { src = Wq; dst = wb;            off = i - 1048576; }
  else if (i < 1572864)  { src = Wk; dst = wb + 1048576;  off = i - 1310720; }
  else if (i < 1835008)  { src = Wv; dst = wb + 2097152;  off = i - 1572864; }
  else                   { src = Wp; dst = wb + 3145728;  off = i - 1835008; }
  const float4 f = ((const float4*)src)[off];
  uint2 o;
  o.x = pk2(f.x, f.y);
  o.y = pk2(f.z, f.w);
  ((uint2*)dst)[off] = o;
}

// ---------------------------------------------------------------------------
// Register-prefetch GEMM: C[row,n] = sum_k A[row,k]*W[n,k], bf16 MFMA core.
// 128x128 block tile, BK=32, 4 waves x (64x64 via 4x4 16x16x32 accs).
// LDS 16KB single buffer, fragment order (subtile s: 64 lanes x 16B at
// s*1024; lane slot = row s*16+(l&15), k (l>>4)*8).
// K-loop per iter:
//   barrier1 (prev ds_reads done; arrived loads drain here - already hidden)
//   ds_write_b128 x4 (staging regs -> LDS, wave's subtiles 2w,2w+1 of A,B)
//   barrier2 (publish; lgkm-dominated)
//   issue buffer_loads for tile i+1 -> regs   <- in flight across compute(i)
//   compute: 8 ds_read_b128 + 16 MFMA
// IS_PROJ=false: grid (32,24), mode=by>>3: 0 q(rope) 1 k(rope) 2 v(blend,
//   transposed [bh][d][t] store); W = Wb + mode*1M.
// IS_PROJ=true: grid (32,8), W=Wb, f32 out.
// ---------------------------------------------------------------------------
template <bool IS_PROJ>
__global__ __launch_bounds__(256) void gemm_rp(
    const u16* __restrict__ Ab, const u16* __restrict__ Wb,
    u16* __restrict__ qo, u16* __restrict__ ko, u16* __restrict__ vto,
    float* __restrict__ fo, const float* __restrict__ v1,
    const float* __restrict__ lambp) {
  __shared__ __attribute__((aligned(16))) unsigned char Asm[8192];
  __shared__ __attribute__((aligned(16))) unsigned char Bsm[8192];
  const int tid  = threadIdx.x;
  const int w    = tid >> 6;
  const int lane = tid & 63;
  const int lo = lane & 15, hi = lane >> 4;
  const int m0 = blockIdx.x << 7;
  const int by = blockIdx.y;
  const int mode = IS_PROJ ? 3 : (by >> 3);
  const int n0 = IS_PROJ ? (by << 7) : ((by & 7) << 7);
  const u16* W = IS_PROJ ? Wb : (Wb + (size_t)mode * (DIM_ * DIM_));

  const int wm = w & 1, wn = w >> 1;

  // staging global pointers: wave w stages subtiles 2w, 2w+1 of A and B
  const u16* agA0 = Ab + (size_t)(m0 + (2 * w + 0) * 16 + lo) * DIM_ + (hi << 3);
  const u16* agA1 = Ab + (size_t)(m0 + (2 * w + 1) * 16 + lo) * DIM_ + (hi << 3);
  const u16* agB0 = W  + (size_t)(n0 + (2 * w + 0) * 16 + lo) * DIM_ + (hi << 3);
  const u16* agB1 = W  + (size_t)(n0 + (2 * w + 1) * 16 + lo) * DIM_ + (hi << 3);
  // per-lane LDS staging slots (byte addr): unit u at u*1024 + lane*16
  unsigned char* dA0 = Asm + (2 * w + 0) * 1024 + (lane << 4);
  unsigned char* dA1 = Asm + (2 * w + 1) * 1024 + (lane << 4);
  unsigned char* dB0 = Bsm + (2 * w + 0) * 1024 + (lane << 4);
  unsigned char* dB1 = Bsm + (2 * w + 1) * 1024 + (lane << 4);

  f32x4 acc[4][4];
#pragma unroll
  for (int i = 0; i < 4; ++i)
#pragma unroll
    for (int j = 0; j < 4; ++j) acc[i][j] = (f32x4){0.f, 0.f, 0.f, 0.f};

  // prologue: load tile 0 into registers
  uint4 ra0 = *(const uint4*)agA0;
  uint4 ra1 = *(const uint4*)agA1;
  uint4 rb0 = *(const uint4*)agB0;
  uint4 rb1 = *(const uint4*)agB1;
  agA0 += 32; agA1 += 32; agB0 += 32; agB1 += 32;

  for (int kc = 0; kc < DIM_; kc += 32) {
    __syncthreads();                 // barrier1: prev iter's ds_reads done
    *(uint4*)dA0 = ra0;
    *(uint4*)dA1 = ra1;
    *(uint4*)dB0 = rb0;
    *(uint4*)dB1 = rb1;
    __syncthreads();                 // barrier2: tile published (lgkm-cheap)
    if (kc + 32 < DIM_) {            // issue next-tile loads; in flight
      ra0 = *(const uint4*)agA0;     // across the whole compute phase
      ra1 = *(const uint4*)agA1;
      rb0 = *(const uint4*)agB0;
      rb1 = *(const uint4*)agB1;
      agA0 += 32; agA1 += 32; agB0 += 32; agB1 += 32;
    }
    bf16x8 bfr[4];
#pragma unroll
    for (int nt = 0; nt < 4; ++nt)
      bfr[nt] = *(const bf16x8*)(Bsm + (((wn * 4 + nt) * 64 + lane) << 4));
#pragma unroll
    for (int mt = 0; mt < 4; ++mt) {
      const bf16x8 af = *(const bf16x8*)(Asm + (((wm * 4 + mt) * 64 + lane) << 4));
#pragma unroll
      for (int nt = 0; nt < 4; ++nt)
        acc[mt][nt] = MFMA16(af, bfr[nt], acc[mt][nt]);
    }
  }

  // ---- register epilogues (r6/r7-verified) ----
  const int head = (n0 >> 6) + wn;
  if (mode <= 1) {
    u16* C = (mode == 0) ? qo : ko;
    const float if0 = exp2f(-(float)lo * (LOG2_10K / 32.f));
    const float if1 = exp2f(-(float)(lo + 16) * (LOG2_10K / 32.f));
#pragma unroll
    for (int mt = 0; mt < 4; ++mt)
#pragma unroll
      for (int r = 0; r < 4; ++r) {
        float ss = 0.f;
#pragma unroll
        for (int nt = 0; nt < 4; ++nt) { const float v = acc[mt][nt][r]; ss += v * v; }
        ss += __shfl_xor(ss, 1, 64); ss += __shfl_xor(ss, 2, 64);
        ss += __shfl_xor(ss, 4, 64); ss += __shfl_xor(ss, 8, 64);
        const float scl = rsqrtf(ss * (1.f / 64.f) + EPS_);
        const int row_g = m0 + wm * 64 + mt * 16 + hi * 4 + r;
        const float tpos = (float)(row_g & (T_ - 1));
        float sn0, cs0, sn1, cs1;
        sincosf(tpos * if0, &sn0, &cs0);
        sincosf(tpos * if1, &sn1, &cs1);
        u16* crow = C + (size_t)row_g * DIM_ + head * HD_;
        const float x10 = acc[mt][0][r] * scl, x11 = acc[mt][1][r] * scl;
        const float x20 = acc[mt][2][r] * scl, x21 = acc[mt][3][r] * scl;
        crow[lo]      = f2b(x10 * cs0 + x20 * sn0);
        crow[16 + lo] = f2b(x11 * cs1 + x21 * sn1);
        crow[32 + lo] = f2b(x20 * cs0 - x10 * sn0);
        crow[48 + lo] = f2b(x21 * cs1 - x11 * sn1);
      }
  } else if (mode == 2) {
    const float lam = lambp[0];
#pragma unroll
    for (int mt = 0; mt < 4; ++mt)
#pragma unroll
      for (int r = 0; r < 4; ++r) {
        const int row_g = m0 + wm * 64 + mt * 16 + hi * 4 + r;
        const int bb = row_g >> 11, tt = row_g & (T_ - 1);
        const int bh = bb * H_ + head;
        const float* v1r = v1 + (size_t)row_g * DIM_ + head * HD_;
#pragma unroll
        for (int nt = 0; nt < 4; ++nt) {
          const int d = nt * 16 + lo;
          const float ov = (1.f - lam) * acc[mt][nt][r] + lam * v1r[d];
          vto[((size_t)(bh * HD_ + d)) * T_ + tt] = f2b(ov);   // transposed
        }
      }
  } else {
#pragma unroll
    for (int mt = 0; mt < 4; ++mt)
#pragma unroll
      for (int r = 0; r < 4; ++r) {
        const int row_g = m0 + wm * 64 + mt * 16 + hi * 4 + r;
        float* orow = fo + (size_t)row_g * DIM_ + n0 + wn * 64;
#pragma unroll
        for (int nt = 0; nt < 4; ++nt) orow[nt * 16 + lo] = acc[mt][nt][r];
      }
  }
}

// ---------------------------------------------------------------------------
// gate[n,h] = sigmoid( sum_{j<12} x[n,j]*Wg[h,j] )
// ---------------------------------------------------------------------------
__global__ __launch_bounds__(256) void gate_kernel(
    const float* __restrict__ x, const float* __restrict__ Wg,
    float* __restrict__ gate) {
  const int id = blockIdx.x * 256 + threadIdx.x;
  const int n = id >> 4, h = id & 15;
  const float* xr = x + (size_t)n * DIM_;
  const float* wr = Wg + h * 12;
  float s = 0.f;
#pragma unroll
  for (int j = 0; j < 12; ++j) s += xr[j] * wr[j];
  gate[id] = 1.f / (1.f + __expf(-s));
}

// ---------------------------------------------------------------------------
// MFMA flash attention, S^T form (r6-verified). Block = (b,h,64-q tile).
// ---------------------------------------------------------------------------
__global__ __launch_bounds__(256) void attn3(
    const u16* __restrict__ q, const u16* __restrict__ k, const u16* __restrict__ vt,
    const float* __restrict__ gate, u16* __restrict__ y) {
  __shared__ __attribute__((aligned(16))) unsigned char smem[16384];
  const int tid = threadIdx.x;
  const int wv = tid >> 6, lane = tid & 63, lo = lane & 15, hi = lane >> 4;
  const int idx = blockIdx.x;
  const int qt = 31 - (idx >> 5);
  const int bh = idx & 31;
  const int b = bh >> 4, h = bh & 15;
  const int qb = qt << 6;

  const int qrow = b * T_ + qb + wv * 16 + lo;
  const u16* qp = q + (size_t)qrow * DIM_ + h * HD_;
  const bf16x8 qf0 = *(const bf16x8*)(qp + hi * 8);
  const bf16x8 qf1 = *(const bf16x8*)(qp + 32 + hi * 8);

  f32x4 o[4];
#pragma unroll
  for (int i = 0; i < 4; ++i) o[i] = (f32x4){0.f, 0.f, 0.f, 0.f};
  float mrun = -1e30f, lrun = 0.f;

  const int sl = tid & 63, skh = (tid >> 6) & 1, st0 = tid >> 7;
  const int srow = sl & 15, skk = skh * 32 + ((sl >> 4) << 3);
  const u16* kg0 = k + ((size_t)(b * T_ + st0 * 16 + srow)) * DIM_ + h * HD_ + skk;
  const u16* kg1 = kg0 + (size_t)32 * DIM_;
  const u16* vg0 = vt + ((size_t)(bh * HD_ + st0 * 16 + srow)) * T_ + skk;
  const u16* vg1 = vg0 + (size_t)32 * T_;

  uint4 kr0 = *(const uint4*)kg0, kr1 = *(const uint4*)kg1;
  uint4 vr0 = *(const uint4*)vg0, vr1 = *(const uint4*)vg1;

  const int off0 = tid << 4, off1 = (tid + 256) << 4;

  for (int tix = 0; tix <= qt; ++tix) {
    __syncthreads();
    *(uint4*)(smem + off0) = kr0;
    *(uint4*)(smem + off1) = kr1;
    *(uint4*)(smem + 8192 + off0) = vr0;
    *(uint4*)(smem + 8192 + off1) = vr1;
    if (tix < qt) {
      const size_t ko = (size_t)(tix + 1) * 64 * DIM_;
      const size_t vo = (size_t)(tix + 1) * 64;
      kr0 = *(const uint4*)(kg0 + ko); kr1 = *(const uint4*)(kg1 + ko);
      vr0 = *(const uint4*)(vg0 + vo); vr1 = *(const uint4*)(vg1 + vo);
    }
    __syncthreads();

    f32x4 stl[4];
#pragma unroll
    for (int kt = 0; kt < 4; ++kt) stl[kt] = (f32x4){0.f, 0.f, 0.f, 0.f};
#pragma unroll
    for (int kh = 0; kh < 2; ++kh) {
      const bf16x8 qb_ = kh ? qf1 : qf0;
#pragma unroll
      for (int kt = 0; kt < 4; ++kt) {
        const bf16x8 af = *(const bf16x8*)(smem + (((kt * 2 + kh) * 64 + lane) << 4));
        stl[kt] = MFMA16(af, qb_, stl[kt]);
      }
    }
    const bool diag = (tix == qt);
#pragma unroll
    for (int kt = 0; kt < 4; ++kt)
#pragma unroll
      for (int r = 0; r < 4; ++r) {
        float s = stl[kt][r] * SCALE_;
        if (diag && (kt * 16 + hi * 4 + r > wv * 16 + lo)) s = -3e38f;
        stl[kt][r] = s;
      }
    float mx = stl[0][0];
#pragma unroll
    for (int kt = 0; kt < 4; ++kt)
#pragma unroll
      for (int r = 0; r < 4; ++r) mx = fmaxf(mx, stl[kt][r]);
    mx = fmaxf(mx, __shfl_xor(mx, 16, 64));
    mx = fmaxf(mx, __shfl_xor(mx, 32, 64));
    const float mn = fmaxf(mrun, mx);
    const float alpha = __expf(mrun - mn);
    mrun = mn;
    float ps = 0.f;
#pragma unroll
    for (int kt = 0; kt < 4; ++kt)
#pragma unroll
      for (int r = 0; r < 4; ++r) { stl[kt][r] = __expf(stl[kt][r] - mn); ps += stl[kt][r]; }
    ps += __shfl_xor(ps, 16, 64);
    ps += __shfl_xor(ps, 32, 64);
    lrun = lrun * alpha + ps;
#pragma unroll
    for (int dt = 0; dt < 4; ++dt) o[dt] *= alpha;

    u32 pkv[4][2];
#pragma unroll
    for (int kt = 0; kt < 4; ++kt) {
      pkv[kt][0] = pk2(stl[kt][0], stl[kt][1]);
      pkv[kt][1] = pk2(stl[kt][2], stl[kt][3]);
    }
#pragma unroll
    for (int kh = 0; kh < 2; ++kh) {
      uint4 w4;
      u32* w4p = (u32*)&w4;
#pragma unroll
      for (int wd = 0; wd < 4; ++wd) {
        const int src = (2 * (hi & 1) + (wd >> 1)) * 16 + lo;
        const u32 a  = (u32)__shfl((int)pkv[2 * kh][wd & 1], src, 64);
        const u32 bb = (u32)__shfl((int)pkv[2 * kh + 1][wd & 1], src, 64);
        w4p[wd] = (hi < 2) ? a : bb;
      }
      const bf16x8 pf = __builtin_bit_cast(bf16x8, w4);
#pragma unroll
      for (int dt = 0; dt < 4; ++dt) {
        const bf16x8 vf = *(const bf16x8*)(smem + 8192 + (((dt * 2 + kh) * 64 + lane) << 4));
        o[dt] = MFMA16(vf, pf, o[dt]);
      }
    }
  }

  const float inv = gate[(size_t)qrow * H_ + h] / lrun;
  u16* yrow = y + (size_t)qrow * DIM_ + h * HD_;
#pragma unroll
  for (int dt = 0; dt < 4; ++dt) {
    ushort4 pq;
    pq.x = f2b(o[dt][0] * inv); pq.y = f2b(o[dt][1] * inv);
    pq.z = f2b(o[dt][2] * inv); pq.w = f2b(o[dt][3] * inv);
    *(ushort4*)(yrow + dt * 16 + hi * 4) = pq;
  }
}

// ---------------------------------------------------------------------------
extern "C" void kernel_launch(void* const* d_in, const int* in_sizes, int n_in,
                              void* d_out, int out_size, void* d_ws, size_t ws_size,
                              hipStream_t stream) {
  const float* x    = (const float*)d_in[0];
  const float* v1   = (const float*)d_in[1];
  const float* Wq   = (const float*)d_in[2];
  const float* Wk   = (const float*)d_in[3];
  const float* Wv   = (const float*)d_in[4];
  const float* Wp   = (const float*)d_in[5];
  const float* Wg   = (const float*)d_in[6];
  const float* lamb = (const float*)d_in[7];

  const size_t NX = (size_t)NROW * DIM_;        // 4M
  const size_t NW = (size_t)DIM_ * DIM_;        // 1M

  u16* q  = (u16*)d_ws;                         // also y (in-place)
  u16* k  = q + NX;
  u16* vt = k + NX;                             // [bh][d][t]
  u16* xb = vt + NX;
  u16* wb = xb + NX;                            // wqb|wkb|wvb|wpb (4M)
  float* gate = (float*)(wb + 4 * NW);          // total ws: 40.25 MB

  const dim3 bb(256);

  convert_all<<<dim3(8192), bb, 0, stream>>>(x, Wq, Wk, Wv, Wp, xb, wb);
  gemm_rp<false><<<dim3(NROW / 128, 24), bb, 0, stream>>>(
      xb, wb, q, k, vt, nullptr, v1, lamb);
  gate_kernel<<<dim3(NROW * H_ / 256), bb, 0, stream>>>(x, Wg, gate);
  attn3<<<dim3(B_ * H_ * (T_ / 64)), bb, 0, stream>>>(q, k, vt, gate, q);
  gemm_rp<true><<<dim3(NROW / 128, 8), bb, 0, stream>>>(
      q, wb + 3 * NW, nullptr, nullptr, nullptr, (float*)d_out, nullptr, nullptr);
}

// Round 10
// 236.836 us; speedup vs baseline: 1.0149x; 1.0149x over previous
//
#include <hip/hip_runtime.h>
#include <math.h>

// ---------------------------------------------------------------------------
// CausalSelfAttention fused pipeline, MI355X gfx950.  Round 10.
// r7/r8/r9: three different K-loop structures all ~98us, MfmaUtil ~10% ->
// K-loop is NOT the bottleneck; the RoPE epilogue's 32 OCML sincosf calls
// per thread (~100+ insts each) are. This round: hardware sin/cos in
// revolutions (fold 1/2pi into freq, v_fract + v_sin_f32/v_cos_f32 = 4 insts
// per pair). Everything else identical to r9.
// Workspace: q(=y) 8MB | k 8MB | vt 8MB | xb 8MB | w[4]b 8MB | gate 256KB.
// ---------------------------------------------------------------------------

#define B_    2
#define T_    2048
#define DIM_  1024
#define H_    16
#define HD_   64
#define NROW  (B_ * T_)
#define EPS_  1.1920929e-07f
#define SCALE_ 0.1f
#define LOG2_10K 13.287712379549449f
#define INV2PI 0.15915494309189535f

typedef unsigned short u16;
typedef unsigned int   u32;
typedef __bf16 bf16x8 __attribute__((ext_vector_type(8)));
typedef __bf16 bf16x2 __attribute__((ext_vector_type(2)));
typedef float  f32x4  __attribute__((ext_vector_type(4)));

__device__ __forceinline__ u16 f2b(float f) {
  u32 u = __float_as_uint(f);
  u += 0x7fffu + ((u >> 16) & 1u);       // RNE
  return (u16)(u >> 16);
}
__device__ __forceinline__ u32 pk2(float a, float b) {
#if __has_builtin(__builtin_amdgcn_cvt_pk_bf16_f32)
  bf16x2 r = __builtin_amdgcn_cvt_pk_bf16_f32(a, b);
  return __builtin_bit_cast(u32, r);
#else
  return (u32)f2b(a) | ((u32)f2b(b) << 16);
#endif
}
// fast sin/cos of (rev revolutions): fract to [0,1), then v_sin/v_cos
__device__ __forceinline__ void fast_sincos_rev(float rev, float* s, float* c) {
  const float r = rev - floorf(rev);
#if __has_builtin(__builtin_amdgcn_sinf) && __has_builtin(__builtin_amdgcn_cosf)
  *s = __builtin_amdgcn_sinf(r);
  *c = __builtin_amdgcn_cosf(r);
#else
  *s = __sinf(r * 6.283185307179586f);
  *c = __cosf(r * 6.283185307179586f);
#endif
}
#define MFMA16(a,b,c) __builtin_amdgcn_mfma_f32_16x16x32_bf16((a),(b),(c),0,0,0)

// ---------------------------------------------------------------------------
// Convert pass: x (4M) and Wq/Wk/Wv/Wp (1M each) f32 -> bf16.
// ---------------------------------------------------------------------------
__global__ __launch_bounds__(256) void convert_all(
    const float* __restrict__ x, const float* __restrict__ Wq,
    const float* __restrict__ Wk, const float* __restrict__ Wv,
    const float* __restrict__ Wp,
    u16* __restrict__ xb, u16* __restrict__ wb /* wqb|wkb|wvb|wpb */) {
  const int i = blockIdx.x * 256 + threadIdx.x;       // 0 .. 2M-1 groups
  const float* src;
  u16* dst;
  int off;
  if (i < 1048576)       { src = x;  dst = xb;            off = i; }
  else if (i < 1310720)  { src = Wq; dst = wb;            off = i - 1048576; }
  else if (i < 1572864)  { src = Wk; dst = wb + 1048576;  off = i - 1310720; }
  else if (i < 1835008)  { src = Wv; dst = wb + 2097152;  off = i - 1572864; }
  else                   { src = Wp; dst = wb + 3145728;  off = i - 1835008; }
  const float4 f = ((const float4*)src)[off];
  uint2 o;
  o.x = pk2(f.x, f.y);
  o.y = pk2(f.z, f.w);
  ((uint2*)dst)[off] = o;
}

// ---------------------------------------------------------------------------
// Register-prefetch GEMM (r9 structure): C[row,n] = sum_k A[row,k]*W[n,k].
// 128x128 block tile, BK=32, 4 waves x (64x64 via 4x4 16x16x32 accs).
// LDS 16KB single buffer, fragment order. K-loop: barrier / ds_write x4 /
// barrier / issue next-tile buffer_loads / 8 ds_read_b128 + 16 MFMA.
// IS_PROJ=false: grid (32,24), mode=by>>3: 0 q(rope) 1 k(rope) 2 v(blend,
//   transposed [bh][d][t] store); W = Wb + mode*1M.
// IS_PROJ=true: grid (32,8), W=Wb, f32 out.
// ---------------------------------------------------------------------------
template <bool IS_PROJ>
__global__ __launch_bounds__(256) void gemm_rp(
    const u16* __restrict__ Ab, const u16* __restrict__ Wb,
    u16* __restrict__ qo, u16* __restrict__ ko, u16* __restrict__ vto,
    float* __restrict__ fo, const float* __restrict__ v1,
    const float* __restrict__ lambp) {
  __shared__ __attribute__((aligned(16))) unsigned char Asm[8192];
  __shared__ __attribute__((aligned(16))) unsigned char Bsm[8192];
  const int tid  = threadIdx.x;
  const int w    = tid >> 6;
  const int lane = tid & 63;
  const int lo = lane & 15, hi = lane >> 4;
  const int m0 = blockIdx.x << 7;
  const int by = blockIdx.y;
  const int mode = IS_PROJ ? 3 : (by >> 3);
  const int n0 = IS_PROJ ? (by << 7) : ((by & 7) << 7);
  const u16* W = IS_PROJ ? Wb : (Wb + (size_t)mode * (DIM_ * DIM_));

  const int wm = w & 1, wn = w >> 1;

  const u16* agA0 = Ab + (size_t)(m0 + (2 * w + 0) * 16 + lo) * DIM_ + (hi << 3);
  const u16* agA1 = Ab + (size_t)(m0 + (2 * w + 1) * 16 + lo) * DIM_ + (hi << 3);
  const u16* agB0 = W  + (size_t)(n0 + (2 * w + 0) * 16 + lo) * DIM_ + (hi << 3);
  const u16* agB1 = W  + (size_t)(n0 + (2 * w + 1) * 16 + lo) * DIM_ + (hi << 3);
  unsigned char* dA0 = Asm + (2 * w + 0) * 1024 + (lane << 4);
  unsigned char* dA1 = Asm + (2 * w + 1) * 1024 + (lane << 4);
  unsigned char* dB0 = Bsm + (2 * w + 0) * 1024 + (lane << 4);
  unsigned char* dB1 = Bsm + (2 * w + 1) * 1024 + (lane << 4);

  f32x4 acc[4][4];
#pragma unroll
  for (int i = 0; i < 4; ++i)
#pragma unroll
    for (int j = 0; j < 4; ++j) acc[i][j] = (f32x4){0.f, 0.f, 0.f, 0.f};

  uint4 ra0 = *(const uint4*)agA0;
  uint4 ra1 = *(const uint4*)agA1;
  uint4 rb0 = *(const uint4*)agB0;
  uint4 rb1 = *(const uint4*)agB1;
  agA0 += 32; agA1 += 32; agB0 += 32; agB1 += 32;

  for (int kc = 0; kc < DIM_; kc += 32) {
    __syncthreads();
    *(uint4*)dA0 = ra0;
    *(uint4*)dA1 = ra1;
    *(uint4*)dB0 = rb0;
    *(uint4*)dB1 = rb1;
    __syncthreads();
    if (kc + 32 < DIM_) {
      ra0 = *(const uint4*)agA0;
      ra1 = *(const uint4*)agA1;
      rb0 = *(const uint4*)agB0;
      rb1 = *(const uint4*)agB1;
      agA0 += 32; agA1 += 32; agB0 += 32; agB1 += 32;
    }
    bf16x8 bfr[4];
#pragma unroll
    for (int nt = 0; nt < 4; ++nt)
      bfr[nt] = *(const bf16x8*)(Bsm + (((wn * 4 + nt) * 64 + lane) << 4));
#pragma unroll
    for (int mt = 0; mt < 4; ++mt) {
      const bf16x8 af = *(const bf16x8*)(Asm + (((wm * 4 + mt) * 64 + lane) << 4));
#pragma unroll
      for (int nt = 0; nt < 4; ++nt)
        acc[mt][nt] = MFMA16(af, bfr[nt], acc[mt][nt]);
    }
  }

  // ---- register epilogues ----
  const int head = (n0 >> 6) + wn;
  if (mode <= 1) {
    u16* C = (mode == 0) ? qo : ko;
    // frequencies in REVOLUTIONS (1/2pi folded in)
    const float if0 = exp2f(-(float)lo * (LOG2_10K / 32.f)) * INV2PI;
    const float if1 = exp2f(-(float)(lo + 16) * (LOG2_10K / 32.f)) * INV2PI;
#pragma unroll
    for (int mt = 0; mt < 4; ++mt)
#pragma unroll
      for (int r = 0; r < 4; ++r) {
        float ss = 0.f;
#pragma unroll
        for (int nt = 0; nt < 4; ++nt) { const float v = acc[mt][nt][r]; ss += v * v; }
        ss += __shfl_xor(ss, 1, 64); ss += __shfl_xor(ss, 2, 64);
        ss += __shfl_xor(ss, 4, 64); ss += __shfl_xor(ss, 8, 64);
        const float scl = rsqrtf(ss * (1.f / 64.f) + EPS_);
        const int row_g = m0 + wm * 64 + mt * 16 + hi * 4 + r;
        const float tpos = (float)(row_g & (T_ - 1));
        float sn0, cs0, sn1, cs1;
        fast_sincos_rev(tpos * if0, &sn0, &cs0);
        fast_sincos_rev(tpos * if1, &sn1, &cs1);
        u16* crow = C + (size_t)row_g * DIM_ + head * HD_;
        const float x10 = acc[mt][0][r] * scl, x11 = acc[mt][1][r] * scl;
        const float x20 = acc[mt][2][r] * scl, x21 = acc[mt][3][r] * scl;
        crow[lo]      = f2b(x10 * cs0 + x20 * sn0);
        crow[16 + lo] = f2b(x11 * cs1 + x21 * sn1);
        crow[32 + lo] = f2b(x20 * cs0 - x10 * sn0);
        crow[48 + lo] = f2b(x21 * cs1 - x11 * sn1);
      }
  } else if (mode == 2) {
    const float lam = lambp[0];
#pragma unroll
    for (int mt = 0; mt < 4; ++mt)
#pragma unroll
      for (int r = 0; r < 4; ++r) {
        const int row_g = m0 + wm * 64 + mt * 16 + hi * 4 + r;
        const int bb = row_g >> 11, tt = row_g & (T_ - 1);
        const int bh = bb * H_ + head;
        const float* v1r = v1 + (size_t)row_g * DIM_ + head * HD_;
#pragma unroll
        for (int nt = 0; nt < 4; ++nt) {
          const int d = nt * 16 + lo;
          const float ov = (1.f - lam) * acc[mt][nt][r] + lam * v1r[d];
          vto[((size_t)(bh * HD_ + d)) * T_ + tt] = f2b(ov);   // transposed
        }
      }
  } else {
#pragma unroll
    for (int mt = 0; mt < 4; ++mt)
#pragma unroll
      for (int r = 0; r < 4; ++r) {
        const int row_g = m0 + wm * 64 + mt * 16 + hi * 4 + r;
        float* orow = fo + (size_t)row_g * DIM_ + n0 + wn * 64;
#pragma unroll
        for (int nt = 0; nt < 4; ++nt) orow[nt * 16 + lo] = acc[mt][nt][r];
      }
  }
}

// ---------------------------------------------------------------------------
// gate[n,h] = sigmoid( sum_{j<12} x[n,j]*Wg[h,j] )
// ---------------------------------------------------------------------------
__global__ __launch_bounds__(256) void gate_kernel(
    const float* __restrict__ x, const float* __restrict__ Wg,
    float* __restrict__ gate) {
  const int id = blockIdx.x * 256 + threadIdx.x;
  const int n = id >> 4, h = id & 15;
  const float* xr = x + (size_t)n * DIM_;
  const float* wr = Wg + h * 12;
  float s = 0.f;
#pragma unroll
  for (int j = 0; j < 12; ++j) s += xr[j] * wr[j];
  gate[id] = 1.f / (1.f + __expf(-s));
}

// ---------------------------------------------------------------------------
// MFMA flash attention, S^T form (r6-verified). Block = (b,h,64-q tile).
// ---------------------------------------------------------------------------
__global__ __launch_bounds__(256) void attn3(
    const u16* __restrict__ q, const u16* __restrict__ k, const u16* __restrict__ vt,
    const float* __restrict__ gate, u16* __restrict__ y) {
  __shared__ __attribute__((aligned(16))) unsigned char smem[16384];
  const int tid = threadIdx.x;
  const int wv = tid >> 6, lane = tid & 63, lo = lane & 15, hi = lane >> 4;
  const int idx = blockIdx.x;
  const int qt = 31 - (idx >> 5);
  const int bh = idx & 31;
  const int b = bh >> 4, h = bh & 15;
  const int qb = qt << 6;

  const int qrow = b * T_ + qb + wv * 16 + lo;
  const u16* qp = q + (size_t)qrow * DIM_ + h * HD_;
  const bf16x8 qf0 = *(const bf16x8*)(qp + hi * 8);
  const bf16x8 qf1 = *(const bf16x8*)(qp + 32 + hi * 8);

  f32x4 o[4];
#pragma unroll
  for (int i = 0; i < 4; ++i) o[i] = (f32x4){0.f, 0.f, 0.f, 0.f};
  float mrun = -1e30f, lrun = 0.f;

  const int sl = tid & 63, skh = (tid >> 6) & 1, st0 = tid >> 7;
  const int srow = sl & 15, skk = skh * 32 + ((sl >> 4) << 3);
  const u16* kg0 = k + ((size_t)(b * T_ + st0 * 16 + srow)) * DIM_ + h * HD_ + skk;
  const u16* kg1 = kg0 + (size_t)32 * DIM_;
  const u16* vg0 = vt + ((size_t)(bh * HD_ + st0 * 16 + srow)) * T_ + skk;
  const u16* vg1 = vg0 + (size_t)32 * T_;

  uint4 kr0 = *(const uint4*)kg0, kr1 = *(const uint4*)kg1;
  uint4 vr0 = *(const uint4*)vg0, vr1 = *(const uint4*)vg1;

  const int off0 = tid << 4, off1 = (tid + 256) << 4;

  for (int tix = 0; tix <= qt; ++tix) {
    __syncthreads();
    *(uint4*)(smem + off0) = kr0;
    *(uint4*)(smem + off1) = kr1;
    *(uint4*)(smem + 8192 + off0) = vr0;
    *(uint4*)(smem + 8192 + off1) = vr1;
    if (tix < qt) {
      const size_t ko = (size_t)(tix + 1) * 64 * DIM_;
      const size_t vo = (size_t)(tix + 1) * 64;
      kr0 = *(const uint4*)(kg0 + ko); kr1 = *(const uint4*)(kg1 + ko);
      vr0 = *(const uint4*)(vg0 + vo); vr1 = *(const uint4*)(vg1 + vo);
    }
    __syncthreads();

    f32x4 stl[4];
#pragma unroll
    for (int kt = 0; kt < 4; ++kt) stl[kt] = (f32x4){0.f, 0.f, 0.f, 0.f};
#pragma unroll
    for (int kh = 0; kh < 2; ++kh) {
      const bf16x8 qb_ = kh ? qf1 : qf0;
#pragma unroll
      for (int kt = 0; kt < 4; ++kt) {
        const bf16x8 af = *(const bf16x8*)(smem + (((kt * 2 + kh) * 64 + lane) << 4));
        stl[kt] = MFMA16(af, qb_, stl[kt]);
      }
    }
    const bool diag = (tix == qt);
#pragma unroll
    for (int kt = 0; kt < 4; ++kt)
#pragma unroll
      for (int r = 0; r < 4; ++r) {
        float s = stl[kt][r] * SCALE_;
        if (diag && (kt * 16 + hi * 4 + r > wv * 16 + lo)) s = -3e38f;
        stl[kt][r] = s;
      }
    float mx = stl[0][0];
#pragma unroll
    for (int kt = 0; kt < 4; ++kt)
#pragma unroll
      for (int r = 0; r < 4; ++r) mx = fmaxf(mx, stl[kt][r]);
    mx = fmaxf(mx, __shfl_xor(mx, 16, 64));
    mx = fmaxf(mx, __shfl_xor(mx, 32, 64));
    const float mn = fmaxf(mrun, mx);
    const float alpha = __expf(mrun - mn);
    mrun = mn;
    float ps = 0.f;
#pragma unroll
    for (int kt = 0; kt < 4; ++kt)
#pragma unroll
      for (int r = 0; r < 4; ++r) { stl[kt][r] = __expf(stl[kt][r] - mn); ps += stl[kt][r]; }
    ps += __shfl_xor(ps, 16, 64);
    ps += __shfl_xor(ps, 32, 64);
    lrun = lrun * alpha + ps;
#pragma unroll
    for (int dt = 0; dt < 4; ++dt) o[dt] *= alpha;

    u32 pkv[4][2];
#pragma unroll
    for (int kt = 0; kt < 4; ++kt) {
      pkv[kt][0] = pk2(stl[kt][0], stl[kt][1]);
      pkv[kt][1] = pk2(stl[kt][2], stl[kt][3]);
    }
#pragma unroll
    for (int kh = 0; kh < 2; ++kh) {
      uint4 w4;
      u32* w4p = (u32*)&w4;
#pragma unroll
      for (int wd = 0; wd < 4; ++wd) {
        const int src = (2 * (hi & 1) + (wd >> 1)) * 16 + lo;
        const u32 a  = (u32)__shfl((int)pkv[2 * kh][wd & 1], src, 64);
        const u32 bb = (u32)__shfl((int)pkv[2 * kh + 1][wd & 1], src, 64);
        w4p[wd] = (hi < 2) ? a : bb;
      }
      const bf16x8 pf = __builtin_bit_cast(bf16x8, w4);
#pragma unroll
      for (int dt = 0; dt < 4; ++dt) {
        const bf16x8 vf = *(const bf16x8*)(smem + 8192 + (((dt * 2 + kh) * 64 + lane) << 4));
        o[dt] = MFMA16(vf, pf, o[dt]);
      }
    }
  }

  const float inv = gate[(size_t)qrow * H_ + h] / lrun;
  u16* yrow = y + (size_t)qrow * DIM_ + h * HD_;
#pragma unroll
  for (int dt = 0; dt < 4; ++dt) {
    ushort4 pq;
    pq.x = f2b(o[dt][0] * inv); pq.y = f2b(o[dt][1] * inv);
    pq.z = f2b(o[dt][2] * inv); pq.w = f2b(o[dt][3] * inv);
    *(ushort4*)(yrow + dt * 16 + hi * 4) = pq;
  }
}

// ---------------------------------------------------------------------------
extern "C" void kernel_launch(void* const* d_in, const int* in_sizes, int n_in,
                              void* d_out, int out_size, void* d_ws, size_t ws_size,
                              hipStream_t stream) {
  const float* x    = (const float*)d_in[0];
  const float* v1   = (const float*)d_in[1];
  const float* Wq   = (const float*)d_in[2];
  const float* Wk   = (const float*)d_in[3];
  const float* Wv   = (const float*)d_in[4];
  const float* Wp   = (const float*)d_in[5];
  const float* Wg   = (const float*)d_in[6];
  const float* lamb = (const float*)d_in[7];

  const size_t NX = (size_t)NROW * DIM_;        // 4M
  const size_t NW = (size_t)DIM_ * DIM_;        // 1M

  u16* q  = (u16*)d_ws;                         // also y (in-place)
  u16* k  = q + NX;
  u16* vt = k + NX;                             // [bh][d][t]
  u16* xb = vt + NX;
  u16* wb = xb + NX;                            // wqb|wkb|wvb|wpb (4M)
  float* gate = (float*)(wb + 4 * NW);          // total ws: 40.25 MB

  const dim3 bb(256);

  convert_all<<<dim3(8192), bb, 0, stream>>>(x, Wq, Wk, Wv, Wp, xb, wb);
  gemm_rp<false><<<dim3(NROW / 128, 24), bb, 0, stream>>>(
      xb, wb, q, k, vt, nullptr, v1, lamb);
  gate_kernel<<<dim3(NROW * H_ / 256), bb, 0, stream>>>(x, Wg, gate);
  attn3<<<dim3(B_ * H_ * (T_ / 64)), bb, 0, stream>>>(q, k, vt, gate, q);
  gemm_rp<true><<<dim3(NROW / 128, 8), bb, 0, stream>>>(
      q, wb + 3 * NW, nullptr, nullptr, nullptr, (float*)d_out, nullptr, nullptr);
}